// Round 5
// baseline (247.830 us; speedup 1.0000x reference)
//
#include <hip/hip_runtime.h>

// BERT-CRF NER, two kernels.
//  K1 feats (v2): X[65536,768] @ W^T[768,13] + b -> featsT[13][65536].
//     1-wave blocks (grid 1024, 64 rows each), X DMA'd via global_load_lds
//     into triple-buffered XOR-swizzled 8KB LDS tiles with counted vmcnt,
//     W read thread-uniform from global (-> s_load/SGPR, off the LDS pipe).
//  K2 viterbi: byte-identical to round 4's passing kernel.
// B=256, T=256, H=768, L=13, START=11.
// Outputs (float32): [0..255] max_p/T; [256..65791] path.

#define NEGV (-10000.0f)

typedef __attribute__((address_space(1))) const void  gvoid;
typedef __attribute__((address_space(3))) void        svoid;

__device__ __forceinline__ void gload_lds16(const float* g, float* lds) {
  __builtin_amdgcn_global_load_lds((gvoid*)g, (svoid*)lds, 16, 0, 0);
}

// ---------------------------------------------------------------- kernel 1 --
// Lane = row. 24 k-chunks of 32 floats. LDS: 3 x (64 rows x 32 floats) = 24 KB
// -> 6 blocks/CU; no __syncthreads anywhere in the main loop (single wave).
// LDS layout: row-major [row][slot], lane stages slot (l&7) of row (i*8+l>>3)
// with k-offset XOR-swizzled on the SOURCE address; compute reads undo it.
__global__ __launch_bounds__(64) void feats_kernel(
    const float* __restrict__ X,      // [65536, 768]
    const float* __restrict__ W,      // [13, 768]
    const float* __restrict__ bias,   // [13]
    float* __restrict__ featsT)       // [13][65536]
{
  __shared__ float Xs[3][64 * 32];    // 3 x 8 KB

  const int l = threadIdx.x;
  const int blk = blockIdx.x;         // 64 rows per block
  const float* Xb = X + (long)blk * (64 * 768);
  const int r0 = l >> 3;              // row-within-8 this lane stages
  const int ksw = (((l & 7) ^ r0) << 2);
  const int l7 = l & 7;

  #define STAGE(c, bi)                                                        \
    {                                                                         \
      const int kbase = (c) * 32;                                             \
      _Pragma("unroll")                                                       \
      for (int i = 0; i < 8; ++i) {                                           \
        const float* src = Xb + (i * 8 + r0) * 768 + kbase + ksw;             \
        float* dst = &Xs[bi][(i * 8) * 32];                                   \
        gload_lds16(src, dst);                                                \
      }                                                                       \
    }

  STAGE(0, 0)
  STAGE(1, 1)
  STAGE(2, 2)

  float acc[13];
  #pragma unroll
  for (int c = 0; c < 13; ++c) acc[c] = 0.0f;

  #pragma unroll 1
  for (int c = 0; c < 24; ++c) {
    if (c < 22)       asm volatile("s_waitcnt vmcnt(16)" ::: "memory");
    else if (c == 22) asm volatile("s_waitcnt vmcnt(8)"  ::: "memory");
    else              asm volatile("s_waitcnt vmcnt(0)"  ::: "memory");

    const float* xrow = &Xs[c % 3][l * 32];
    const float* wbase = W + c * 32;          // GLOBAL, thread-uniform
    #pragma unroll
    for (int j = 0; j < 8; ++j) {
      float4 x = *reinterpret_cast<const float4*>(xrow + ((j ^ l7) << 2));
      #pragma unroll
      for (int col = 0; col < 13; ++col) {
        float4 wv = *reinterpret_cast<const float4*>(wbase + col * 768 + j * 4);
        acc[col] = fmaf(x.x, wv.x, acc[col]);
        acc[col] = fmaf(x.y, wv.y, acc[col]);
        acc[col] = fmaf(x.z, wv.z, acc[col]);
        acc[col] = fmaf(x.w, wv.w, acc[col]);
      }
    }
    // LDS reads of this buffer must complete before its DMA overwrite
    asm volatile("s_waitcnt lgkmcnt(0)" ::: "memory");
    if (c + 3 < 24) STAGE(c + 3, (c + 3) % 3)
  }
  #undef STAGE

  const long rowG = (long)blk * 64 + l;
  #pragma unroll
  for (int col = 0; col < 13; ++col)
    featsT[(long)col * 65536 + rowG] = acc[col] + bias[col];
}

// ---------------------------------------------------------------- kernel 2 --
// (byte-identical to round 4's passing viterbi kernel)
__global__ __launch_bounds__(256) void viterbi_kernel(
    const float* __restrict__ featsT,  // [13][65536]
    const float* __restrict__ trans,   // [13,13]
    float* __restrict__ out)           // [256 + 65536]
{
  __shared__ float fsT[13 * 260];          // feats transposed [to][t] (pad 260)
  __shared__ float lds_ld[256 * 16];       // ld_t[to], t = 0..255
  __shared__ float trL[176];               // trans (169 used)
  __shared__ unsigned char psi[256 * 16];  // psi[t][to]
  __shared__ unsigned char Mm[256];        // [16 chunks][16]
  __shared__ unsigned char bnd[16];
  __shared__ unsigned char path[256];

  const int tid = threadIdx.x;
  const int w = tid >> 6, lane = tid & 63;
  const int b = blockIdx.x;

  #pragma unroll
  for (int i = 0; i < 13; ++i)
    fsT[i * 260 + tid] = featsT[(long)i * 65536 + b * 256 + tid];
  if (tid < 169) trL[tid] = trans[tid];
  __syncthreads();

  // ---- phase 1: serial forward (values only), wave 0, lower half-wave ----
  if (w == 0 && lane < 16) {
    float tr[13];
    #pragma unroll
    for (int f = 0; f < 13; ++f)
      tr[f] = (lane < 13) ? trans[lane * 13 + f] : -1.0e30f;

    const int toc = (lane < 13) ? lane : 0;
    const float* frow = &fsT[toc * 260];

    float ld = (lane == 11) ? 0.0f : NEGV;  // START = 11
    if (lane < 13) lds_ld[lane] = ld;       // t = 0

    float4 F[4], Fn[4];
    #pragma unroll
    for (int q = 0; q < 4; ++q)
      F[q] = *reinterpret_cast<const float4*>(frow + 4 * q);

    #pragma unroll 1
    for (int g = 0; g < 16; ++g) {
      if (g < 15) {
        #pragma unroll
        for (int q = 0; q < 4; ++q)
          Fn[q] = *reinterpret_cast<const float4*>(frow + (g + 1) * 16 + 4 * q);
      }
      const int kLo = (g == 0) ? 1 : 0;     // skip t = 0
      #pragma unroll
      for (int k = 0; k < 16; ++k) {
        if (k < kLo) continue;
        const int t = g * 16 + k;
        float c[13];
        #pragma unroll
        for (int f = 0; f < 13; ++f) {
          float lf = __uint_as_float(
              __builtin_amdgcn_readlane(__float_as_uint(ld), f));
          c[f] = tr[f] + lf;
        }
        float p0 = fmaxf(fmaxf(c[0], c[1]), c[2]);
        float p1 = fmaxf(fmaxf(c[3], c[4]), c[5]);
        float p2 = fmaxf(fmaxf(c[6], c[7]), c[8]);
        float p3 = fmaxf(fmaxf(c[9], c[10]), c[11]);
        float m  = fmaxf(fmaxf(fmaxf(p0, p1), p2), fmaxf(p3, c[12]));

        const float4 fq = F[k >> 2];
        const float ft = ((k & 3) == 0) ? fq.x : ((k & 3) == 1) ? fq.y
                        : ((k & 3) == 2) ? fq.z : fq.w;
        ld = m + ft;
        if (lane < 13) lds_ld[t * 16 + lane] = ld;
      }
      #pragma unroll
      for (int q = 0; q < 4; ++q) F[q] = Fn[q];
    }
  }
  __syncthreads();

  // ---- phase 2: psi in parallel over t ----
  {
    const int to = tid & 15, dtt = tid >> 4;
    if (to < 13) {
      float trr[13];
      #pragma unroll
      for (int f = 0; f < 13; ++f) trr[f] = trL[to * 13 + f];
      for (int t = (dtt == 0 ? 16 : dtt); t < 256; t += 16) {
        const float* lp = &lds_ld[(t - 1) * 16];
        float4 l0 = *reinterpret_cast<const float4*>(lp);
        float4 l1 = *reinterpret_cast<const float4*>(lp + 4);
        float4 l2 = *reinterpret_cast<const float4*>(lp + 8);
        float4 l3 = *reinterpret_cast<const float4*>(lp + 12);
        float c[13] = {trr[0] + l0.x,  trr[1] + l0.y,  trr[2] + l0.z,
                       trr[3] + l0.w,  trr[4] + l1.x,  trr[5] + l1.y,
                       trr[6] + l1.z,  trr[7] + l1.w,  trr[8] + l2.x,
                       trr[9] + l2.y,  trr[10] + l2.z, trr[11] + l2.w,
                       trr[12] + l3.x};
        float best = c[0]; int bf = 0;
        #pragma unroll
        for (int f = 1; f < 13; ++f) {
          bool gt = c[f] > best;              // strict >: first index wins
          best = gt ? c[f] : best;
          bf   = gt ? f : bf;
        }
        psi[t * 16 + to] = (unsigned char)bf;
      }
    }
  }
  __syncthreads();

  // ---- phase 3: ancestor maps ----
  {
    const int s = tid & 15, g = tid >> 4;
    if (s < 13) {
      int cur = s;
      const int tLo = (g == 0) ? 1 : g * 16;
      for (int t = g * 16 + 15; t >= tLo; --t)
        cur = psi[t * 16 + cur];
      Mm[g * 16 + s] = (unsigned char)cur;
    }
  }
  __syncthreads();

  // ---- phase 4: softmax output + boundary chase ----
  if (tid == 0) {
    const float* lf = &lds_ld[255 * 16];
    float m = lf[0]; int last = 0;
    #pragma unroll
    for (int i = 1; i < 13; ++i)
      if (lf[i] > m) { m = lf[i]; last = i; }   // strict >: first index
    float s = 0.0f;
    #pragma unroll
    for (int i = 0; i < 13; ++i) s += expf(lf[i] - m);
    out[b] = 1.0f / (256.0f * s);               // max(softmax)/T

    int cur = last;
    bnd[15] = (unsigned char)cur;
    #pragma unroll
    for (int cc = 15; cc >= 1; --cc) {
      cur = Mm[cc * 16 + cur];
      bnd[cc - 1] = (unsigned char)cur;
    }
  }
  __syncthreads();

  // ---- phase 5: interior chases ----
  if (tid < 16) {
    int cur = bnd[tid];
    const int tHi = tid * 16 + 15;
    path[tHi] = (unsigned char)cur;
    const int tLo = (tid == 0) ? 1 : tid * 16;
    for (int t = tHi; t >= tLo; --t) {
      cur = psi[t * 16 + cur];
      path[t - 1] = (unsigned char)cur;
    }
  }
  __syncthreads();

  out[256 + (long)b * 256 + tid] = (float)path[tid];
}

// ------------------------------------------------------------------ launch --
extern "C" void kernel_launch(void* const* d_in, const int* in_sizes, int n_in,
                              void* d_out, int out_size, void* d_ws, size_t ws_size,
                              hipStream_t stream) {
  const float* X     = (const float*)d_in[0];
  const float* W     = (const float*)d_in[1];
  const float* bias  = (const float*)d_in[2];
  const float* trans = (const float*)d_in[3];
  float* out    = (float*)d_out;
  float* featsT = (float*)d_ws;   // 13*65536 floats = 3.4 MB

  feats_kernel<<<1024, 64, 0, stream>>>(X, W, bias, featsT);
  viterbi_kernel<<<256, 256, 0, stream>>>(featsT, trans, out);
}

// Round 6
// 134.747 us; speedup vs baseline: 1.8392x; 1.8392x over previous
//
#include <hip/hip_runtime.h>

// Fused BERT-CRF NER: one block per batch (grid 256, block 256 = 4 waves).
// Feats phase: X[256,768] @ W^T + b with W entirely in VGPRs (156 regs/lane,
//   butterfly layout), X DMA'd via global_load_lds into double-buffered 48KB
//   16-row slabs (identity layout -> perfectly coalesced; wave-private rows ->
//   no barriers), counted vmcnt. Results go straight to LDS fsT[13][260].
// Viterbi phase: instruction-identical to round-4's passing kernel (value-only
//   serial forward, parallel psi recompute, ancestor maps, parallel backtrace).
// B=256, T=256, H=768, L=13, START=11.
// Outputs (float32): [0..255] max_p/T; [256..65791] path.

#define NEGV (-10000.0f)

typedef __attribute__((address_space(1))) const void  gvoid;
typedef __attribute__((address_space(3))) void        svoid;

__device__ __forceinline__ void gload_lds16(const float* g, float* lds) {
  __builtin_amdgcn_global_load_lds((gvoid*)g, (svoid*)lds, 16, 0, 0);
}

__global__ __launch_bounds__(256, 1) void fused_kernel(
    const float* __restrict__ X,      // [65536, 768]
    const float* __restrict__ W,      // [13, 768]
    const float* __restrict__ bias,   // [13]
    const float* __restrict__ trans,  // [13,13]
    float* __restrict__ out)          // [256 + 65536]
{
  __shared__ float slab[2][16 * 768];      // 2 x 48 KB X slabs
  __shared__ float fsT[13 * 260];          // feats transposed [to][t]
  __shared__ float lds_ld[256 * 16];       // ld_t[to]
  __shared__ float trL[176];               // trans (169 used)
  __shared__ unsigned char psi[256 * 16];  // psi[t][to]
  __shared__ unsigned char Mm[256];        // [16 chunks][16]
  __shared__ unsigned char bnd[16];
  __shared__ unsigned char path[256];

  const int tid = threadIdx.x;
  const int w = tid >> 6, l = tid & 63;
  const int b = blockIdx.x;
  const float* Xb = X + (long)b * (256 * 768);

  // ---- prologue: W -> VGPRs (butterfly slice: lane l holds k in
  //      {4l..4l+3, 256+4l.., 512+4l..} for each col), bias, trans->LDS ----
  float wreg[13][12];
  #pragma unroll
  for (int col = 0; col < 13; ++col) {
    #pragma unroll
    for (int j = 0; j < 3; ++j) {
      float4 v = *reinterpret_cast<const float4*>(W + col * 768 + 256 * j + 4 * l);
      wreg[col][4 * j + 0] = v.x; wreg[col][4 * j + 1] = v.y;
      wreg[col][4 * j + 2] = v.z; wreg[col][4 * j + 3] = v.w;
    }
  }
  float bv = (l < 13) ? bias[l] : 0.0f;
  if (tid < 169) trL[tid] = trans[tid];
  asm volatile("s_waitcnt vmcnt(0)" ::: "memory");  // drain W/bias/trans loads

  // wave w DMAs ONLY its rows [4w..4w+4) of each 16-row slab; LDS layout is an
  // identity copy of global ([16][768] row-major) so loads are 1KB contiguous.
  #define STAGE_SLAB(s)                                                       \
    {                                                                         \
      const float* srcB = Xb + (s) * 12288 + w * 3072 + l * 4;                \
      float* dstB = &slab[(s) & 1][w * 3072];                                 \
      _Pragma("unroll")                                                       \
      for (int i = 0; i < 12; ++i)                                            \
        gload_lds16(srcB + i * 256, dstB + i * 256);                          \
    }

  STAGE_SLAB(0)
  STAGE_SLAB(1)

  // ---- feats main loop: 16 slabs, 4 rows/wave/slab, butterfly reduce ----
  #pragma unroll 1
  for (int s = 0; s < 16; ++s) {
    if (s < 15) asm volatile("s_waitcnt vmcnt(12)" ::: "memory");
    else        asm volatile("s_waitcnt vmcnt(0)"  ::: "memory");

    const float* sb = &slab[s & 1][0];
    #pragma unroll 1
    for (int t4 = 0; t4 < 4; ++t4) {
      const int r = 4 * w + t4;           // slab-row (wave-private)
      float x[12];
      #pragma unroll
      for (int j = 0; j < 3; ++j) {
        float4 v = *reinterpret_cast<const float4*>(sb + 768 * r + 256 * j + 4 * l);
        x[4 * j + 0] = v.x; x[4 * j + 1] = v.y;
        x[4 * j + 2] = v.z; x[4 * j + 3] = v.w;
      }
      float acc[13];
      #pragma unroll
      for (int c = 0; c < 13; ++c) acc[c] = 0.0f;
      #pragma unroll
      for (int col = 0; col < 13; ++col)
        #pragma unroll
        for (int k = 0; k < 12; ++k)
          acc[col] = fmaf(x[k], wreg[col][k], acc[col]);

      // 64-lane butterfly allreduce (identical order to the passing r1 kernel)
      #pragma unroll
      for (int c = 0; c < 13; ++c) {
        float v = acc[c];
        v += __shfl_xor(v, 1);
        v += __shfl_xor(v, 2);
        v += __shfl_xor(v, 4);
        v += __shfl_xor(v, 8);
        v += __shfl_xor(v, 16);
        v += __shfl_xor(v, 32);
        acc[c] = v;
      }
      float v = acc[0];
      #pragma unroll
      for (int c = 1; c < 13; ++c) v = (l == c) ? acc[c] : v;
      v += bv;
      const int t = s * 16 + r;           // absolute timestep in this batch
      if (l < 13) fsT[l * 260 + t] = v;
    }
    asm volatile("s_waitcnt lgkmcnt(0)" ::: "memory");  // reads done pre-overwrite
    if (s + 2 < 16) STAGE_SLAB(s + 2)
  }
  #undef STAGE_SLAB
  __syncthreads();

  // ======================= viterbi (round-4 verbatim) =======================
  const int lane = l;

  // ---- phase 1: serial forward (values only), wave 0, lower half-wave ----
  if (w == 0 && lane < 16) {
    float tr[13];
    #pragma unroll
    for (int f = 0; f < 13; ++f)
      tr[f] = (lane < 13) ? trans[lane * 13 + f] : -1.0e30f;

    const int toc = (lane < 13) ? lane : 0;
    const float* frow = &fsT[toc * 260];

    float ld = (lane == 11) ? 0.0f : NEGV;  // START = 11
    if (lane < 13) lds_ld[lane] = ld;       // t = 0

    float4 F[4], Fn[4];
    #pragma unroll
    for (int q = 0; q < 4; ++q)
      F[q] = *reinterpret_cast<const float4*>(frow + 4 * q);

    #pragma unroll 1
    for (int g = 0; g < 16; ++g) {
      if (g < 15) {
        #pragma unroll
        for (int q = 0; q < 4; ++q)
          Fn[q] = *reinterpret_cast<const float4*>(frow + (g + 1) * 16 + 4 * q);
      }
      const int kLo = (g == 0) ? 1 : 0;     // skip t = 0
      #pragma unroll
      for (int k = 0; k < 16; ++k) {
        if (k < kLo) continue;
        const int t = g * 16 + k;
        float c[13];
        #pragma unroll
        for (int f = 0; f < 13; ++f) {
          float lf = __uint_as_float(
              __builtin_amdgcn_readlane(__float_as_uint(ld), f));
          c[f] = tr[f] + lf;
        }
        float p0 = fmaxf(fmaxf(c[0], c[1]), c[2]);
        float p1 = fmaxf(fmaxf(c[3], c[4]), c[5]);
        float p2 = fmaxf(fmaxf(c[6], c[7]), c[8]);
        float p3 = fmaxf(fmaxf(c[9], c[10]), c[11]);
        float m  = fmaxf(fmaxf(fmaxf(p0, p1), p2), fmaxf(p3, c[12]));

        const float4 fq = F[k >> 2];
        const float ft = ((k & 3) == 0) ? fq.x : ((k & 3) == 1) ? fq.y
                        : ((k & 3) == 2) ? fq.z : fq.w;
        ld = m + ft;
        if (lane < 13) lds_ld[t * 16 + lane] = ld;
      }
      #pragma unroll
      for (int q = 0; q < 4; ++q) F[q] = Fn[q];
    }
  }
  __syncthreads();

  // ---- phase 2: psi in parallel over t ----
  {
    const int to = tid & 15, dtt = tid >> 4;
    if (to < 13) {
      float trr[13];
      #pragma unroll
      for (int f = 0; f < 13; ++f) trr[f] = trL[to * 13 + f];
      for (int t = (dtt == 0 ? 16 : dtt); t < 256; t += 16) {
        const float* lp = &lds_ld[(t - 1) * 16];
        float4 l0 = *reinterpret_cast<const float4*>(lp);
        float4 l1 = *reinterpret_cast<const float4*>(lp + 4);
        float4 l2 = *reinterpret_cast<const float4*>(lp + 8);
        float4 l3 = *reinterpret_cast<const float4*>(lp + 12);
        float c[13] = {trr[0] + l0.x,  trr[1] + l0.y,  trr[2] + l0.z,
                       trr[3] + l0.w,  trr[4] + l1.x,  trr[5] + l1.y,
                       trr[6] + l1.z,  trr[7] + l1.w,  trr[8] + l2.x,
                       trr[9] + l2.y,  trr[10] + l2.z, trr[11] + l2.w,
                       trr[12] + l3.x};
        float best = c[0]; int bf = 0;
        #pragma unroll
        for (int f = 1; f < 13; ++f) {
          bool gt = c[f] > best;              // strict >: first index wins
          best = gt ? c[f] : best;
          bf   = gt ? f : bf;
        }
        psi[t * 16 + to] = (unsigned char)bf;
      }
    }
  }
  __syncthreads();

  // ---- phase 3: ancestor maps ----
  {
    const int sS = tid & 15, g = tid >> 4;
    if (sS < 13) {
      int cur = sS;
      const int tLo = (g == 0) ? 1 : g * 16;
      for (int t = g * 16 + 15; t >= tLo; --t)
        cur = psi[t * 16 + cur];
      Mm[g * 16 + sS] = (unsigned char)cur;
    }
  }
  __syncthreads();

  // ---- phase 4: softmax output + boundary chase ----
  if (tid == 0) {
    const float* lf = &lds_ld[255 * 16];
    float m = lf[0]; int last = 0;
    #pragma unroll
    for (int i = 1; i < 13; ++i)
      if (lf[i] > m) { m = lf[i]; last = i; }   // strict >: first index
    float ssum = 0.0f;
    #pragma unroll
    for (int i = 0; i < 13; ++i) ssum += expf(lf[i] - m);
    out[b] = 1.0f / (256.0f * ssum);            // max(softmax)/T

    int cur = last;
    bnd[15] = (unsigned char)cur;
    #pragma unroll
    for (int cc = 15; cc >= 1; --cc) {
      cur = Mm[cc * 16 + cur];
      bnd[cc - 1] = (unsigned char)cur;
    }
  }
  __syncthreads();

  // ---- phase 5: interior chases ----
  if (tid < 16) {
    int cur = bnd[tid];
    const int tHi = tid * 16 + 15;
    path[tHi] = (unsigned char)cur;
    const int tLo = (tid == 0) ? 1 : tid * 16;
    for (int t = tHi; t >= tLo; --t) {
      cur = psi[t * 16 + cur];
      path[t - 1] = (unsigned char)cur;
    }
  }
  __syncthreads();

  out[256 + (long)b * 256 + tid] = (float)path[tid];
}

// ------------------------------------------------------------------ launch --
extern "C" void kernel_launch(void* const* d_in, const int* in_sizes, int n_in,
                              void* d_out, int out_size, void* d_ws, size_t ws_size,
                              hipStream_t stream) {
  const float* X     = (const float*)d_in[0];
  const float* W     = (const float*)d_in[1];
  const float* bias  = (const float*)d_in[2];
  const float* trans = (const float*)d_in[3];
  float* out = (float*)d_out;

  fused_kernel<<<256, 256, 0, stream>>>(X, W, bias, trans, out);
}

// Round 7
// 110.073 us; speedup vs baseline: 2.2515x; 1.2242x over previous
//
#include <hip/hip_runtime.h>

// BERT-CRF NER, two kernels.
//  K1 feats (v3): X[65536,768] @ W^T + b -> featsT[13][65536].
//     ZERO LDS. W in VGPRs (156 regs, butterfly slice). X loaded as plain
//     coalesced float4 -> registers with 1-row prefetch (12 KB in flight per
//     wave). Grid 512 x 256 -> 8 waves/CU (VGPR-capped occupancy).
//     FMA/butterfly order bit-identical to the round-1 passing kernel.
//  K2 viterbi: byte-identical to round 4's passing kernel.
// B=256, T=256, H=768, L=13, START=11.
// Outputs (float32): [0..255] max_p/T; [256..65791] path.

#define NEGV (-10000.0f)

// ---------------------------------------------------------------- kernel 1 --
// Wave = butterfly unit; lane l owns k-slice {4l..4l+3, 256+4l.., 512+4l..}.
// Each wave computes 32 consecutive rows; block (4 waves) = 128 rows.
__global__ __launch_bounds__(256) void feats_kernel(
    const float* __restrict__ X,      // [65536, 768]
    const float* __restrict__ W,      // [13, 768]
    const float* __restrict__ bias,   // [13]
    float* __restrict__ featsT)       // [13][65536]
{
  const int tid = threadIdx.x;
  const int w = tid >> 6, l = tid & 63;
  const long row0 = (long)blockIdx.x * 128 + w * 32;

  // W -> VGPRs, butterfly slice (one-time; L1/L2-cached across waves)
  float wreg[13][12];
  #pragma unroll
  for (int col = 0; col < 13; ++col) {
    #pragma unroll
    for (int j = 0; j < 3; ++j) {
      float4 v = *reinterpret_cast<const float4*>(W + col * 768 + 256 * j + 4 * l);
      wreg[col][4 * j + 0] = v.x; wreg[col][4 * j + 1] = v.y;
      wreg[col][4 * j + 2] = v.z; wreg[col][4 * j + 3] = v.w;
    }
  }
  const float bv = bias[(l < 13) ? l : 0];

  const float* xp = X + row0 * 768 + 4 * l;

  // prefetch row 0
  float4 xa0 = *reinterpret_cast<const float4*>(xp);
  float4 xa1 = *reinterpret_cast<const float4*>(xp + 256);
  float4 xa2 = *reinterpret_cast<const float4*>(xp + 512);

  #pragma unroll 1
  for (int r = 0; r < 32; ++r) {
    float4 xb0, xb1, xb2;
    if (r < 31) {                       // issue next row's loads first (ILP)
      const float* xn = xp + (r + 1) * 768;
      xb0 = *reinterpret_cast<const float4*>(xn);
      xb1 = *reinterpret_cast<const float4*>(xn + 256);
      xb2 = *reinterpret_cast<const float4*>(xn + 512);
    }

    const float x[12] = {xa0.x, xa0.y, xa0.z, xa0.w,
                         xa1.x, xa1.y, xa1.z, xa1.w,
                         xa2.x, xa2.y, xa2.z, xa2.w};
    float acc[13];
    #pragma unroll
    for (int c = 0; c < 13; ++c) acc[c] = 0.0f;
    #pragma unroll
    for (int col = 0; col < 13; ++col)
      #pragma unroll
      for (int k = 0; k < 12; ++k)
        acc[col] = fmaf(x[k], wreg[col][k], acc[col]);

    // 64-lane butterfly allreduce (identical order to round-1 passing kernel)
    #pragma unroll
    for (int c = 0; c < 13; ++c) {
      float v = acc[c];
      v += __shfl_xor(v, 1);
      v += __shfl_xor(v, 2);
      v += __shfl_xor(v, 4);
      v += __shfl_xor(v, 8);
      v += __shfl_xor(v, 16);
      v += __shfl_xor(v, 32);
      acc[c] = v;
    }
    float v = acc[0];
    #pragma unroll
    for (int c = 1; c < 13; ++c) v = (l == c) ? acc[c] : v;
    v += bv;
    if (l < 13) featsT[(long)l * 65536 + row0 + r] = v;

    xa0 = xb0; xa1 = xb1; xa2 = xb2;    // advance pipeline
  }
}

// ---------------------------------------------------------------- kernel 2 --
// (byte-identical to round 4's passing viterbi kernel)
__global__ __launch_bounds__(256) void viterbi_kernel(
    const float* __restrict__ featsT,  // [13][65536]
    const float* __restrict__ trans,   // [13,13]
    float* __restrict__ out)           // [256 + 65536]
{
  __shared__ float fsT[13 * 260];          // feats transposed [to][t] (pad 260)
  __shared__ float lds_ld[256 * 16];       // ld_t[to], t = 0..255
  __shared__ float trL[176];               // trans (169 used)
  __shared__ unsigned char psi[256 * 16];  // psi[t][to]
  __shared__ unsigned char Mm[256];        // [16 chunks][16]
  __shared__ unsigned char bnd[16];
  __shared__ unsigned char path[256];

  const int tid = threadIdx.x;
  const int w = tid >> 6, lane = tid & 63;
  const int b = blockIdx.x;

  #pragma unroll
  for (int i = 0; i < 13; ++i)
    fsT[i * 260 + tid] = featsT[(long)i * 65536 + b * 256 + tid];
  if (tid < 169) trL[tid] = trans[tid];
  __syncthreads();

  // ---- phase 1: serial forward (values only), wave 0, lower half-wave ----
  if (w == 0 && lane < 16) {
    float tr[13];
    #pragma unroll
    for (int f = 0; f < 13; ++f)
      tr[f] = (lane < 13) ? trans[lane * 13 + f] : -1.0e30f;

    const int toc = (lane < 13) ? lane : 0;
    const float* frow = &fsT[toc * 260];

    float ld = (lane == 11) ? 0.0f : NEGV;  // START = 11
    if (lane < 13) lds_ld[lane] = ld;       // t = 0

    float4 F[4], Fn[4];
    #pragma unroll
    for (int q = 0; q < 4; ++q)
      F[q] = *reinterpret_cast<const float4*>(frow + 4 * q);

    #pragma unroll 1
    for (int g = 0; g < 16; ++g) {
      if (g < 15) {
        #pragma unroll
        for (int q = 0; q < 4; ++q)
          Fn[q] = *reinterpret_cast<const float4*>(frow + (g + 1) * 16 + 4 * q);
      }
      const int kLo = (g == 0) ? 1 : 0;     // skip t = 0
      #pragma unroll
      for (int k = 0; k < 16; ++k) {
        if (k < kLo) continue;
        const int t = g * 16 + k;
        float c[13];
        #pragma unroll
        for (int f = 0; f < 13; ++f) {
          float lf = __uint_as_float(
              __builtin_amdgcn_readlane(__float_as_uint(ld), f));
          c[f] = tr[f] + lf;
        }
        float p0 = fmaxf(fmaxf(c[0], c[1]), c[2]);
        float p1 = fmaxf(fmaxf(c[3], c[4]), c[5]);
        float p2 = fmaxf(fmaxf(c[6], c[7]), c[8]);
        float p3 = fmaxf(fmaxf(c[9], c[10]), c[11]);
        float m  = fmaxf(fmaxf(fmaxf(p0, p1), p2), fmaxf(p3, c[12]));

        const float4 fq = F[k >> 2];
        const float ft = ((k & 3) == 0) ? fq.x : ((k & 3) == 1) ? fq.y
                        : ((k & 3) == 2) ? fq.z : fq.w;
        ld = m + ft;
        if (lane < 13) lds_ld[t * 16 + lane] = ld;
      }
      #pragma unroll
      for (int q = 0; q < 4; ++q) F[q] = Fn[q];
    }
  }
  __syncthreads();

  // ---- phase 2: psi in parallel over t ----
  {
    const int to = tid & 15, dtt = tid >> 4;
    if (to < 13) {
      float trr[13];
      #pragma unroll
      for (int f = 0; f < 13; ++f) trr[f] = trL[to * 13 + f];
      for (int t = (dtt == 0 ? 16 : dtt); t < 256; t += 16) {
        const float* lp = &lds_ld[(t - 1) * 16];
        float4 l0 = *reinterpret_cast<const float4*>(lp);
        float4 l1 = *reinterpret_cast<const float4*>(lp + 4);
        float4 l2 = *reinterpret_cast<const float4*>(lp + 8);
        float4 l3 = *reinterpret_cast<const float4*>(lp + 12);
        float c[13] = {trr[0] + l0.x,  trr[1] + l0.y,  trr[2] + l0.z,
                       trr[3] + l0.w,  trr[4] + l1.x,  trr[5] + l1.y,
                       trr[6] + l1.z,  trr[7] + l1.w,  trr[8] + l2.x,
                       trr[9] + l2.y,  trr[10] + l2.z, trr[11] + l2.w,
                       trr[12] + l3.x};
        float best = c[0]; int bf = 0;
        #pragma unroll
        for (int f = 1; f < 13; ++f) {
          bool gt = c[f] > best;              // strict >: first index wins
          best = gt ? c[f] : best;
          bf   = gt ? f : bf;
        }
        psi[t * 16 + to] = (unsigned char)bf;
      }
    }
  }
  __syncthreads();

  // ---- phase 3: ancestor maps ----
  {
    const int sS = tid & 15, g = tid >> 4;
    if (sS < 13) {
      int cur = sS;
      const int tLo = (g == 0) ? 1 : g * 16;
      for (int t = g * 16 + 15; t >= tLo; --t)
        cur = psi[t * 16 + cur];
      Mm[g * 16 + sS] = (unsigned char)cur;
    }
  }
  __syncthreads();

  // ---- phase 4: softmax output + boundary chase ----
  if (tid == 0) {
    const float* lf = &lds_ld[255 * 16];
    float m = lf[0]; int last = 0;
    #pragma unroll
    for (int i = 1; i < 13; ++i)
      if (lf[i] > m) { m = lf[i]; last = i; }   // strict >: first index
    float ssum = 0.0f;
    #pragma unroll
    for (int i = 0; i < 13; ++i) ssum += expf(lf[i] - m);
    out[b] = 1.0f / (256.0f * ssum);            // max(softmax)/T

    int cur = last;
    bnd[15] = (unsigned char)cur;
    #pragma unroll
    for (int cc = 15; cc >= 1; --cc) {
      cur = Mm[cc * 16 + cur];
      bnd[cc - 1] = (unsigned char)cur;
    }
  }
  __syncthreads();

  // ---- phase 5: interior chases ----
  if (tid < 16) {
    int cur = bnd[tid];
    const int tHi = tid * 16 + 15;
    path[tHi] = (unsigned char)cur;
    const int tLo = (tid == 0) ? 1 : tid * 16;
    for (int t = tHi; t >= tLo; --t) {
      cur = psi[t * 16 + cur];
      path[t - 1] = (unsigned char)cur;
    }
  }
  __syncthreads();

  out[256 + (long)b * 256 + tid] = (float)path[tid];
}

// ------------------------------------------------------------------ launch --
extern "C" void kernel_launch(void* const* d_in, const int* in_sizes, int n_in,
                              void* d_out, int out_size, void* d_ws, size_t ws_size,
                              hipStream_t stream) {
  const float* X     = (const float*)d_in[0];
  const float* W     = (const float*)d_in[1];
  const float* bias  = (const float*)d_in[2];
  const float* trans = (const float*)d_in[3];
  float* out    = (float*)d_out;
  float* featsT = (float*)d_ws;   // 13*65536 floats = 3.4 MB

  feats_kernel<<<512, 256, 0, stream>>>(X, W, bias, featsT);
  viterbi_kernel<<<256, 256, 0, stream>>>(featsT, trans, out);
}

// Round 9
// 91.635 us; speedup vs baseline: 2.7045x; 1.2012x over previous
//
#include <hip/hip_runtime.h>

// BERT-CRF NER, two kernels.
//  K1 feats (v4b): X[65536,768] @ W^T + b -> featsT[13][65536].
//     ZERO LDS, zero DS-pipe ops. W in VGPRs (156 regs, k-slice layout).
//     X via coalesced float4 loads with 1-row prefetch. Cross-lane reduction
//     via DPP (row_shr 1/2/4/8 + row_bcast 15/31 fused v_add) = pure VALU;
//     totals read from lane 63 (readlane) and placed in lane c via a
//     cndmask select chain (no writelane builtin on gfx950 toolchain).
//  K2 viterbi: byte-identical to round 4's passing kernel.
// B=256, T=256, H=768, L=13, START=11.
// Outputs (float32): [0..255] max_p/T; [256..65791] path.

#define NEGV (-10000.0f)

// v += dpp_move(v) entirely on the VALU pipe. ctrl/rmask are literals.
#define DPP_ADD(v, ctrl, rmask)                                               \
  v += __int_as_float(__builtin_amdgcn_update_dpp(                            \
      0, __float_as_int(v), (ctrl), (rmask), 0xF, true));

// full 64-lane sum -> lane 63 holds the total
#define DPP_REDUCE64(v)                                                       \
  DPP_ADD(v, 0x111, 0xF)  /* row_shr:1  */                                    \
  DPP_ADD(v, 0x112, 0xF)  /* row_shr:2  */                                    \
  DPP_ADD(v, 0x114, 0xF)  /* row_shr:4  */                                    \
  DPP_ADD(v, 0x118, 0xF)  /* row_shr:8  */                                    \
  DPP_ADD(v, 0x142, 0xA)  /* row_bcast:15 -> rows 1,3 */                      \
  DPP_ADD(v, 0x143, 0xC)  /* row_bcast:31 -> rows 2,3 */

// ---------------------------------------------------------------- kernel 1 --
// Wave = reduction unit; lane l owns k-slice {4l..4l+3, 256+4l.., 512+4l..}.
// Each wave computes 32 consecutive rows; block (4 waves) = 128 rows.
__global__ __launch_bounds__(256) void feats_kernel(
    const float* __restrict__ X,      // [65536, 768]
    const float* __restrict__ W,      // [13, 768]
    const float* __restrict__ bias,   // [13]
    float* __restrict__ featsT)       // [13][65536]
{
  const int tid = threadIdx.x;
  const int w = tid >> 6, l = tid & 63;
  const long row0 = (long)blockIdx.x * 128 + w * 32;

  // W -> VGPRs, k-slice layout (one-time; L2-cached across waves)
  float wreg[13][12];
  #pragma unroll
  for (int col = 0; col < 13; ++col) {
    #pragma unroll
    for (int j = 0; j < 3; ++j) {
      float4 v = *reinterpret_cast<const float4*>(W + col * 768 + 256 * j + 4 * l);
      wreg[col][4 * j + 0] = v.x; wreg[col][4 * j + 1] = v.y;
      wreg[col][4 * j + 2] = v.z; wreg[col][4 * j + 3] = v.w;
    }
  }
  const float bv = bias[(l < 13) ? l : 0];

  const float* xp = X + row0 * 768 + 4 * l;

  // prefetch row 0
  float4 xa0 = *reinterpret_cast<const float4*>(xp);
  float4 xa1 = *reinterpret_cast<const float4*>(xp + 256);
  float4 xa2 = *reinterpret_cast<const float4*>(xp + 512);

  #pragma unroll 1
  for (int r = 0; r < 32; ++r) {
    float4 xb0, xb1, xb2;
    if (r < 31) {                       // issue next row's loads first (ILP)
      const float* xn = xp + (r + 1) * 768;
      xb0 = *reinterpret_cast<const float4*>(xn);
      xb1 = *reinterpret_cast<const float4*>(xn + 256);
      xb2 = *reinterpret_cast<const float4*>(xn + 512);
    }

    const float x[12] = {xa0.x, xa0.y, xa0.z, xa0.w,
                         xa1.x, xa1.y, xa1.z, xa1.w,
                         xa2.x, xa2.y, xa2.z, xa2.w};
    float acc[13];
    #pragma unroll
    for (int c = 0; c < 13; ++c) acc[c] = 0.0f;
    #pragma unroll
    for (int col = 0; col < 13; ++col)
      #pragma unroll
      for (int k = 0; k < 12; ++k)
        acc[col] = fmaf(x[k], wreg[col][k], acc[col]);

    // 13 independent DPP tree-sums (VALU pipe only; chains interleave)
    #pragma unroll
    for (int c = 0; c < 13; ++c) {
      DPP_REDUCE64(acc[c])
    }

    // totals live in lane 63; broadcast each to scalar, lane c selects its own
    float v = __uint_as_float(
        __builtin_amdgcn_readlane(__float_as_uint(acc[0]), 63));
    #pragma unroll
    for (int c = 1; c < 13; ++c) {
      float tc = __uint_as_float(
          __builtin_amdgcn_readlane(__float_as_uint(acc[c]), 63));
      v = (l == c) ? tc : v;            // v_cndmask, pure VALU
    }
    v += bv;
    if (l < 13) featsT[(long)l * 65536 + row0 + r] = v;

    xa0 = xb0; xa1 = xb1; xa2 = xb2;    // advance pipeline
  }
}

// ---------------------------------------------------------------- kernel 2 --
// (byte-identical to round 4's passing viterbi kernel)
__global__ __launch_bounds__(256) void viterbi_kernel(
    const float* __restrict__ featsT,  // [13][65536]
    const float* __restrict__ trans,   // [13,13]
    float* __restrict__ out)           // [256 + 65536]
{
  __shared__ float fsT[13 * 260];          // feats transposed [to][t] (pad 260)
  __shared__ float lds_ld[256 * 16];       // ld_t[to], t = 0..255
  __shared__ float trL[176];               // trans (169 used)
  __shared__ unsigned char psi[256 * 16];  // psi[t][to]
  __shared__ unsigned char Mm[256];        // [16 chunks][16]
  __shared__ unsigned char bnd[16];
  __shared__ unsigned char path[256];

  const int tid = threadIdx.x;
  const int w = tid >> 6, lane = tid & 63;
  const int b = blockIdx.x;

  #pragma unroll
  for (int i = 0; i < 13; ++i)
    fsT[i * 260 + tid] = featsT[(long)i * 65536 + b * 256 + tid];
  if (tid < 169) trL[tid] = trans[tid];
  __syncthreads();

  // ---- phase 1: serial forward (values only), wave 0, lower half-wave ----
  if (w == 0 && lane < 16) {
    float tr[13];
    #pragma unroll
    for (int f = 0; f < 13; ++f)
      tr[f] = (lane < 13) ? trans[lane * 13 + f] : -1.0e30f;

    const int toc = (lane < 13) ? lane : 0;
    const float* frow = &fsT[toc * 260];

    float ld = (lane == 11) ? 0.0f : NEGV;  // START = 11
    if (lane < 13) lds_ld[lane] = ld;       // t = 0

    float4 F[4], Fn[4];
    #pragma unroll
    for (int q = 0; q < 4; ++q)
      F[q] = *reinterpret_cast<const float4*>(frow + 4 * q);

    #pragma unroll 1
    for (int g = 0; g < 16; ++g) {
      if (g < 15) {
        #pragma unroll
        for (int q = 0; q < 4; ++q)
          Fn[q] = *reinterpret_cast<const float4*>(frow + (g + 1) * 16 + 4 * q);
      }
      const int kLo = (g == 0) ? 1 : 0;     // skip t = 0
      #pragma unroll
      for (int k = 0; k < 16; ++k) {
        if (k < kLo) continue;
        const int t = g * 16 + k;
        float c[13];
        #pragma unroll
        for (int f = 0; f < 13; ++f) {
          float lf = __uint_as_float(
              __builtin_amdgcn_readlane(__float_as_uint(ld), f));
          c[f] = tr[f] + lf;
        }
        float p0 = fmaxf(fmaxf(c[0], c[1]), c[2]);
        float p1 = fmaxf(fmaxf(c[3], c[4]), c[5]);
        float p2 = fmaxf(fmaxf(c[6], c[7]), c[8]);
        float p3 = fmaxf(fmaxf(c[9], c[10]), c[11]);
        float m  = fmaxf(fmaxf(fmaxf(p0, p1), p2), fmaxf(p3, c[12]));

        const float4 fq = F[k >> 2];
        const float ft = ((k & 3) == 0) ? fq.x : ((k & 3) == 1) ? fq.y
                        : ((k & 3) == 2) ? fq.z : fq.w;
        ld = m + ft;
        if (lane < 13) lds_ld[t * 16 + lane] = ld;
      }
      #pragma unroll
      for (int q = 0; q < 4; ++q) F[q] = Fn[q];
    }
  }
  __syncthreads();

  // ---- phase 2: psi in parallel over t ----
  {
    const int to = tid & 15, dtt = tid >> 4;
    if (to < 13) {
      float trr[13];
      #pragma unroll
      for (int f = 0; f < 13; ++f) trr[f] = trL[to * 13 + f];
      for (int t = (dtt == 0 ? 16 : dtt); t < 256; t += 16) {
        const float* lp = &lds_ld[(t - 1) * 16];
        float4 l0 = *reinterpret_cast<const float4*>(lp);
        float4 l1 = *reinterpret_cast<const float4*>(lp + 4);
        float4 l2 = *reinterpret_cast<const float4*>(lp + 8);
        float4 l3 = *reinterpret_cast<const float4*>(lp + 12);
        float c[13] = {trr[0] + l0.x,  trr[1] + l0.y,  trr[2] + l0.z,
                       trr[3] + l0.w,  trr[4] + l1.x,  trr[5] + l1.y,
                       trr[6] + l1.z,  trr[7] + l1.w,  trr[8] + l2.x,
                       trr[9] + l2.y,  trr[10] + l2.z, trr[11] + l2.w,
                       trr[12] + l3.x};
        float best = c[0]; int bf = 0;
        #pragma unroll
        for (int f = 1; f < 13; ++f) {
          bool gt = c[f] > best;              // strict >: first index wins
          best = gt ? c[f] : best;
          bf   = gt ? f : bf;
        }
        psi[t * 16 + to] = (unsigned char)bf;
      }
    }
  }
  __syncthreads();

  // ---- phase 3: ancestor maps ----
  {
    const int sS = tid & 15, g = tid >> 4;
    if (sS < 13) {
      int cur = sS;
      const int tLo = (g == 0) ? 1 : g * 16;
      for (int t = g * 16 + 15; t >= tLo; --t)
        cur = psi[t * 16 + cur];
      Mm[g * 16 + sS] = (unsigned char)cur;
    }
  }
  __syncthreads();

  // ---- phase 4: softmax output + boundary chase ----
  if (tid == 0) {
    const float* lf = &lds_ld[255 * 16];
    float m = lf[0]; int last = 0;
    #pragma unroll
    for (int i = 1; i < 13; ++i)
      if (lf[i] > m) { m = lf[i]; last = i; }   // strict >: first index
    float ssum = 0.0f;
    #pragma unroll
    for (int i = 0; i < 13; ++i) ssum += expf(lf[i] - m);
    out[b] = 1.0f / (256.0f * ssum);            // max(softmax)/T

    int cur = last;
    bnd[15] = (unsigned char)cur;
    #pragma unroll
    for (int cc = 15; cc >= 1; --cc) {
      cur = Mm[cc * 16 + cur];
      bnd[cc - 1] = (unsigned char)cur;
    }
  }
  __syncthreads();

  // ---- phase 5: interior chases ----
  if (tid < 16) {
    int cur = bnd[tid];
    const int tHi = tid * 16 + 15;
    path[tHi] = (unsigned char)cur;
    const int tLo = (tid == 0) ? 1 : tid * 16;
    for (int t = tHi; t >= tLo; --t) {
      cur = psi[t * 16 + cur];
      path[t - 1] = (unsigned char)cur;
    }
  }
  __syncthreads();

  out[256 + (long)b * 256 + tid] = (float)path[tid];
}

// ------------------------------------------------------------------ launch --
extern "C" void kernel_launch(void* const* d_in, const int* in_sizes, int n_in,
                              void* d_out, int out_size, void* d_ws, size_t ws_size,
                              hipStream_t stream) {
  const float* X     = (const float*)d_in[0];
  const float* W     = (const float*)d_in[1];
  const float* bias  = (const float*)d_in[2];
  const float* trans = (const float*)d_in[3];
  float* out    = (float*)d_out;
  float* featsT = (float*)d_ws;   // 13*65536 floats = 3.4 MB

  feats_kernel<<<512, 256, 0, stream>>>(X, W, bias, featsT);
  viterbi_kernel<<<256, 256, 0, stream>>>(featsT, trans, out);
}